// Round 8
// baseline (9392.609 us; speedup 1.0000x reference)
//
#include <hip/hip_runtime.h>
#include <math.h>

#define BATCH  64
#define TSTEPS 2048
#define EMBED  300
#define HID    256
#define GATES  1024  // 4*HID

typedef __fp16 h2 __attribute__((ext_vector_type(2)));   // matches cvt_pkrtz/fdot2

__device__ __forceinline__ h2 pack_h2(float a, float b) {
    return __builtin_amdgcn_cvt_pkrtz(a, b);
}
__device__ __forceinline__ h2 bc_h2(unsigned u) {
    return __builtin_bit_cast(h2, u);
}
__device__ __forceinline__ float dot2f(h2 w, h2 h, float acc) {
#if __has_builtin(__builtin_amdgcn_fdot2)
    return __builtin_amdgcn_fdot2(w, h, acc, false);   // f32 accumulate
#else
    return acc + (float)w[0]*(float)h[0] + (float)w[1]*(float)h[1];
#endif
}
__device__ __forceinline__ float rcpf_(float x) {
#if __has_builtin(__builtin_amdgcn_rcpf)
    return __builtin_amdgcn_rcpf(x);
#else
    return 1.0f / x;
#endif
}
// native-exp activations; saturate correctly at +/-inf
__device__ __forceinline__ float sigm_(float x) { return rcpf_(1.f + __expf(-x)); }
__device__ __forceinline__ float tanh_(float x) { return 1.f - 2.f*rcpf_(__expf(2.f*x) + 1.f); }

// ---------------- Kernel 1: per-chunk compaction of update steps ------------
__global__ __launch_bounds__(256) void k_compact(
    const float* __restrict__ mask, const int* __restrict__ lengths,
    int* __restrict__ list, int* __restrict__ cnt,
    float* __restrict__ h_state, float* __restrict__ c_state,
    int t0, int CT, int first_chunk)
{
    int b = blockIdx.x, tid = threadIdx.x;
    if (first_chunk) {
        h_state[b*HID + tid] = 0.f;   // blockDim == HID
        c_state[b*HID + tid] = 0.f;
    }
    int idx = lengths[b] - 1;
    idx = idx < 0 ? 0 : (idx > TSTEPS-1 ? TSTEPS-1 : idx);

    __shared__ int wcnt[4];
    __shared__ int running;
    if (tid == 0) running = 0;
    __syncthreads();

    for (int base = 0; base < CT; base += 256) {
        int t = t0 + base + tid;
        bool pred = ((base + tid) < CT) && (t <= idx)
                    && (mask[b*TSTEPS + t] >= 0.5f);
        unsigned long long bal = __ballot(pred);
        int wave = tid >> 6, lane = tid & 63;
        if (lane == 0) wcnt[wave] = __popcll(bal);
        __syncthreads();
        int off = running;
        for (int w2 = 0; w2 < wave; ++w2) off += wcnt[w2];
        off += __popcll(bal & ((1ull << lane) - 1ull));
        if (pred) list[b*CT + off] = t;
        __syncthreads();
        if (tid == 0) running += wcnt[0] + wcnt[1] + wcnt[2] + wcnt[3];
        __syncthreads();
    }
    if (tid == 0) cnt[b] = running;
}

// ---------------- Kernel 2: gathered GEMM  Z[b,j,:] = x[b,t_j,:] @ W_ih^T ---
__global__ __launch_bounds__(256) void k_gemm(
    const float* __restrict__ emb, const float* __restrict__ W_ih,
    const int* __restrict__ list, const int* __restrict__ cnt,
    float* __restrict__ Z, int CT)
{
    int b = blockIdx.z;
    int mb = cnt[b];
    int i0 = blockIdx.y * 64;
    if (i0 >= mb) return;
    int n0 = blockIdx.x * 64;
    int tid = threadIdx.x;

    __shared__ float As[64][65];
    __shared__ float Bs[64][65];
    __shared__ int   tl[64];

    if (tid < 64) {
        int j = i0 + tid;
        tl[tid] = (j < mb) ? list[b*CT + j] : 0;
    }
    __syncthreads();

    float acc[4][4] = {};
    int tr = tid >> 4, tc = tid & 15;

    for (int k0 = 0; k0 < EMBED; k0 += 64) {
        #pragma unroll
        for (int e = 0; e < 16; ++e) {
            int flat = tid + 256*e;
            int r = flat >> 6, k = flat & 63;
            int j = i0 + r;
            float va = 0.f, vb = 0.f;
            if (k0 + k < EMBED) {
                if (j < mb)
                    va = emb[((size_t)(b*TSTEPS + tl[r]))*EMBED + k0 + k];
                vb = W_ih[(size_t)(n0 + r)*EMBED + k0 + k];
            }
            As[r][k] = va;
            Bs[r][k] = vb;
        }
        __syncthreads();
        #pragma unroll 8
        for (int k = 0; k < 64; ++k) {
            float a0 = As[tr*4+0][k], a1 = As[tr*4+1][k];
            float a2 = As[tr*4+2][k], a3 = As[tr*4+3][k];
            float b0 = Bs[tc*4+0][k], b1 = Bs[tc*4+1][k];
            float b2 = Bs[tc*4+2][k], b3 = Bs[tc*4+3][k];
            acc[0][0] += a0*b0; acc[0][1] += a0*b1; acc[0][2] += a0*b2; acc[0][3] += a0*b3;
            acc[1][0] += a1*b0; acc[1][1] += a1*b1; acc[1][2] += a1*b2; acc[1][3] += a1*b3;
            acc[2][0] += a2*b0; acc[2][1] += a2*b1; acc[2][2] += a2*b2; acc[2][3] += a2*b3;
            acc[3][0] += a3*b0; acc[3][1] += a3*b1; acc[3][2] += a3*b2; acc[3][3] += a3*b3;
        }
        __syncthreads();
    }

    #pragma unroll
    for (int e = 0; e < 4; ++e) {
        int j = i0 + tr*4 + e;
        if (j < mb) {
            size_t zb = ((size_t)b*CT + j)*GATES + n0 + tc*4;
            Z[zb+0] = acc[e][0]; Z[zb+1] = acc[e][1];
            Z[zb+2] = acc[e][2]; Z[zb+3] = acc[e][3];
        }
    }
}

// ---------------- Kernel 3: recurrent LSTM — ONE block per batch ------------
// 512 threads (8 waves, 2/SIMD -> 256-reg cap). Thread t: parity p=t&1,
// dim d=t>>1. Even lane owns gate-rows {i(d), g(d)}, odd lane {f(d), o(d)}.
// Gate exchange = 2 intra-wave shfl_xor (lanes 2d,2d+1 same wave) -> ONE
// barrier per step (double-buffered f16 h). W_hh f16: k<64 in LDS (147KB,
// stride 36 dw, b128 even-bank-spread), k in [64,256) as 2x96 h2 in VGPRs.
// Fast native activations (v_exp+v_rcp) replace libm tanhf/expf.
__global__ __launch_bounds__(512, 2) void k_lstm(
    const float* __restrict__ Z, const int* __restrict__ cnt,
    const float* __restrict__ W_hh,
    const float* __restrict__ b_ih, const float* __restrict__ b_hh,
    float* __restrict__ h_state, float* __restrict__ c_state, int CT)
{
    int b = blockIdx.x;
    int t = threadIdx.x;          // 0..511
    int p = t & 1;                // 0: {i,g}, 1: {f,o}
    int d = t >> 1;               // hidden dim 0..255
    int rowA = p*256 + d;         // gate i or f
    int rowB = p*256 + 512 + d;   // gate g or o

    __shared__ __align__(16) unsigned wlds[1024*36];   // 147,456 B
    __shared__ __align__(16) unsigned h16[2][128];     // 2 x 256 f16

    // stage W[:, k<64] as f16 (row-stride 36 dwords, b128-aligned chunks)
    for (int i = t; i < 1024*8; i += 512) {
        int r = i >> 3, c4 = i & 7;
        const float* src = W_hh + (size_t)r*HID + c4*8;
        uint4 u;
        u.x = __builtin_bit_cast(unsigned, pack_h2(src[0], src[1]));
        u.y = __builtin_bit_cast(unsigned, pack_h2(src[2], src[3]));
        u.z = __builtin_bit_cast(unsigned, pack_h2(src[4], src[5]));
        u.w = __builtin_bit_cast(unsigned, pack_h2(src[6], src[7]));
        *((uint4*)&wlds[r*36 + c4*4]) = u;
    }
    // W[:, 64..255] in registers: 96 h2 per row, 2 rows
    h2 wrA[96], wrB[96];
    {
        const float2* pA = (const float2*)(W_hh + (size_t)rowA*HID);
        const float2* pB = (const float2*)(W_hh + (size_t)rowB*HID);
        #pragma unroll
        for (int q = 0; q < 96; ++q) {
            float2 va = pA[32+q], vb = pB[32+q];
            wrA[q] = pack_h2(va.x, va.y);
            wrB[q] = pack_h2(vb.x, vb.y);
        }
    }
    float biasA = b_ih[rowA] + b_hh[rowA];
    float biasB = b_ih[rowB] + b_hh[rowB];

    float c_reg = c_state[(size_t)b*HID + d];   // both lanes of the pair
    if (t < 256)
        ((_Float16*)h16[0])[t] = (_Float16)h_state[(size_t)b*HID + t];
    __syncthreads();

    int mb = cnt[b];
    float zA = (mb > 0) ? Z[((size_t)b*CT)*GATES + rowA] : 0.f;
    float zB = (mb > 0) ? Z[((size_t)b*CT)*GATES + rowB] : 0.f;
    int cur = 0;

    for (int j = 0; j < mb; ++j) {
        float zAn = 0.f, zBn = 0.f;
        if (j + 1 < mb) {
            zAn = Z[((size_t)b*CT + j + 1)*GATES + rowA];
            zBn = Z[((size_t)b*CT + j + 1)*GATES + rowB];
        }
        const uint4* hbuf = (const uint4*)h16[cur];
        float a0 = 0.f, a1 = 0.f, b0 = 0.f, b1 = 0.f;
        #pragma unroll
        for (int c = 0; c < 32; ++c) {
            uint4 hv = hbuf[c];                       // broadcast: 8 f16 of h
            h2 h0 = bc_h2(hv.x), h1 = bc_h2(hv.y);
            h2 hx = bc_h2(hv.z), h3 = bc_h2(hv.w);
            h2 wA0, wA1, wA2, wA3, wB0, wB1, wB2, wB3;
            if (c < 8) {
                uint4 wa = *((const uint4*)&wlds[rowA*36 + c*4]);
                uint4 wb = *((const uint4*)&wlds[rowB*36 + c*4]);
                wA0 = bc_h2(wa.x); wA1 = bc_h2(wa.y);
                wA2 = bc_h2(wa.z); wA3 = bc_h2(wa.w);
                wB0 = bc_h2(wb.x); wB1 = bc_h2(wb.y);
                wB2 = bc_h2(wb.z); wB3 = bc_h2(wb.w);
            } else {
                int q = (c - 8) * 4;
                wA0 = wrA[q+0]; wA1 = wrA[q+1]; wA2 = wrA[q+2]; wA3 = wrA[q+3];
                wB0 = wrB[q+0]; wB1 = wrB[q+1]; wB2 = wrB[q+2]; wB3 = wrB[q+3];
            }
            a0 = dot2f(wA0, h0, a0); a1 = dot2f(wA1, h1, a1);
            a0 = dot2f(wA2, hx, a0); a1 = dot2f(wA3, h3, a1);
            b0 = dot2f(wB0, h0, b0); b1 = dot2f(wB1, h1, b1);
            b0 = dot2f(wB2, hx, b0); b1 = dot2f(wB3, h3, b1);
        }
        float aA = zA + biasA + (a0 + a1);   // i (p=0) or f (p=1)
        float aB = zB + biasB + (b0 + b1);   // g (p=0) or o (p=1)

        float vA = sigm_(aA);                    // i or f
        float vB = p ? sigm_(aB) : tanh_(aB);    // o or g
        float oA = __shfl_xor(vA, 1, 64);        // partner's i/f
        float oB = __shfl_xor(vB, 1, 64);        // partner's g/o
        float iv = p ? oA : vA;
        float fv = p ? vA : oA;
        float gv = p ? oB : vB;
        float ov = p ? vB : oB;
        c_reg = fv * c_reg + iv * gv;            // identical on both lanes
        float hn = ov * tanh_(c_reg);
        if (!p) ((_Float16*)h16[cur ^ 1])[d] = (_Float16)hn;
        __syncthreads();                          // the ONLY barrier per step
        cur ^= 1;
        zA = zAn; zB = zBn;
    }

    if (!p) {
        h_state[(size_t)b*HID + d] = (float)((_Float16*)h16[cur])[d];
        c_state[(size_t)b*HID + d] = c_reg;
    }
}

// ---------------- Kernel 4: logits -> softmax -> argmax ---------------------
__global__ __launch_bounds__(64) void k_final(
    const float* __restrict__ h_state, const float* __restrict__ W_out,
    const float* __restrict__ b_out, float* __restrict__ out)
{
    int b = threadIdx.x;   // 64 threads
    float l0 = b_out[0], l1 = b_out[1];
    for (int k = 0; k < HID; ++k) {
        float h = h_state[b*HID + k];
        l0 += h * W_out[k];
        l1 += h * W_out[HID + k];
    }
    float m  = fmaxf(l0, l1);
    float e0 = expf(l0 - m), e1 = expf(l1 - m);
    float s  = e0 + e1;
    float p0 = e0 / s, p1 = e1 / s;
    out[b*2 + 0] = p0;
    out[b*2 + 1] = p1;
    out[BATCH*2 + b] = (p1 > p0) ? 1.0f : 0.0f;  // argmax, first-index tiebreak
}

// ---------------- host ------------------------------------------------------
extern "C" void kernel_launch(void* const* d_in, const int* in_sizes, int n_in,
                              void* d_out, int out_size, void* d_ws, size_t ws_size,
                              hipStream_t stream)
{
    (void)in_sizes; (void)n_in; (void)out_size;
    const float* emb   = (const float*)d_in[0];
    const float* mask  = (const float*)d_in[1];
    const int*   len   = (const int*)  d_in[2];
    const float* W_ih  = (const float*)d_in[3];
    const float* W_hh  = (const float*)d_in[4];
    const float* b_ih  = (const float*)d_in[5];
    const float* b_hh  = (const float*)d_in[6];
    const float* W_out = (const float*)d_in[7];
    const float* b_out = (const float*)d_in[8];
    float* out = (float*)d_out;

    char* p = (char*)d_ws;
    auto carve = [&](size_t bytes) -> char* {
        char* r = p;
        p += (bytes + 255) & ~(size_t)255;
        return r;
    };
    float* h_state = (float*)carve((size_t)BATCH*HID*4);
    float* c_state = (float*)carve((size_t)BATCH*HID*4);
    int*   cntb    = (int*)  carve((size_t)BATCH*4);

    size_t fixed = (size_t)(p - (char*)d_ws);
    int CT = TSTEPS;  // shrink to fit workspace
    while (CT > 64) {
        size_t lb = (((size_t)BATCH*CT*4) + 255) & ~(size_t)255;
        size_t zb = (size_t)BATCH*CT*GATES*4;
        if (fixed + lb + zb + 1024 <= ws_size) break;
        CT >>= 1;
    }
    int*   list = (int*)  carve((size_t)BATCH*CT*4);
    float* Z    = (float*)carve((size_t)BATCH*CT*GATES*4);

    int nchunks = TSTEPS / CT;
    for (int c = 0; c < nchunks; ++c) {
        int t0 = c * CT;
        int first = (c == 0) ? 1 : 0;
        hipLaunchKernelGGL(k_compact, dim3(BATCH), dim3(256), 0, stream,
                           mask, len, list, cntb, h_state, c_state,
                           t0, CT, first);
        hipLaunchKernelGGL(k_gemm, dim3(16, CT/64, BATCH), dim3(256), 0, stream,
                           emb, W_ih, list, cntb, Z, CT);
        hipLaunchKernelGGL(k_lstm, dim3(BATCH), dim3(512), 0, stream,
                           Z, cntb, W_hh, b_ih, b_hh,
                           h_state, c_state, CT);
    }
    hipLaunchKernelGGL(k_final, dim3(1), dim3(64), 0, stream,
                       h_state, W_out, b_out, out);
}

// Round 9
// 2601.466 us; speedup vs baseline: 3.6105x; 3.6105x over previous
//
#include <hip/hip_runtime.h>
#include <math.h>

#define BATCH  64
#define TSTEPS 2048
#define EMBED  300
#define HID    256
#define GATES  1024  // 4*HID
#define WSTRIDE 34   // dwords per row of LDS-resident W half (64 f16 = 32 dw + 2 pad)

typedef __fp16 h2 __attribute__((ext_vector_type(2)));   // matches cvt_pkrtz/fdot2

__device__ __forceinline__ h2 pack_h2(float a, float b) {
    return __builtin_amdgcn_cvt_pkrtz(a, b);
}
__device__ __forceinline__ h2 bc_h2(unsigned u) {
    return __builtin_bit_cast(h2, u);
}
__device__ __forceinline__ float dot2f(h2 w, h2 h, float acc) {
#if __has_builtin(__builtin_amdgcn_fdot2)
    return __builtin_amdgcn_fdot2(w, h, acc, false);   // f32 accumulate
#else
    return acc + (float)w[0]*(float)h[0] + (float)w[1]*(float)h[1];
#endif
}
__device__ __forceinline__ float rcpf_(float x) {
#if __has_builtin(__builtin_amdgcn_rcpf)
    return __builtin_amdgcn_rcpf(x);
#else
    return 1.0f / x;
#endif
}
// native-exp activations (v_exp_f32 + v_rcp_f32); saturate correctly at +/-inf
__device__ __forceinline__ float sigm_(float x) { return rcpf_(1.f + __expf(-x)); }
__device__ __forceinline__ float tanh_(float x) { return 1.f - 2.f*rcpf_(__expf(2.f*x) + 1.f); }

// ---------------- Kernel 1: per-chunk compaction of update steps ------------
// grid: 64 blocks (one per batch), 256 threads
__global__ __launch_bounds__(256) void k_compact(
    const float* __restrict__ mask, const int* __restrict__ lengths,
    int* __restrict__ list, int* __restrict__ cnt,
    float* __restrict__ h_state, float* __restrict__ c_state,
    int t0, int CT, int first_chunk)
{
    int b = blockIdx.x, tid = threadIdx.x;
    if (first_chunk) {
        h_state[b*HID + tid] = 0.f;   // blockDim == HID
        c_state[b*HID + tid] = 0.f;
    }
    int idx = lengths[b] - 1;
    idx = idx < 0 ? 0 : (idx > TSTEPS-1 ? TSTEPS-1 : idx);

    __shared__ int wcnt[4];
    __shared__ int running;
    if (tid == 0) running = 0;
    __syncthreads();

    for (int base = 0; base < CT; base += 256) {
        int t = t0 + base + tid;
        bool pred = ((base + tid) < CT) && (t <= idx)
                    && (mask[b*TSTEPS + t] >= 0.5f);
        unsigned long long bal = __ballot(pred);
        int wave = tid >> 6, lane = tid & 63;
        if (lane == 0) wcnt[wave] = __popcll(bal);
        __syncthreads();
        int off = running;
        for (int w2 = 0; w2 < wave; ++w2) off += wcnt[w2];
        off += __popcll(bal & ((1ull << lane) - 1ull));
        if (pred) list[b*CT + off] = t;
        __syncthreads();
        if (tid == 0) running += wcnt[0] + wcnt[1] + wcnt[2] + wcnt[3];
        __syncthreads();
    }
    if (tid == 0) cnt[b] = running;
}

// ---------------- Kernel 2: gathered GEMM  Z[b,j,:] = x[b,t_j,:] @ W_ih^T ---
// grid: (16 col-tiles, CT/64 row-tiles, 64 batches), 256 threads
__global__ __launch_bounds__(256) void k_gemm(
    const float* __restrict__ emb, const float* __restrict__ W_ih,
    const int* __restrict__ list, const int* __restrict__ cnt,
    float* __restrict__ Z, int CT)
{
    int b = blockIdx.z;
    int mb = cnt[b];
    int i0 = blockIdx.y * 64;
    if (i0 >= mb) return;
    int n0 = blockIdx.x * 64;
    int tid = threadIdx.x;

    __shared__ float As[64][65];
    __shared__ float Bs[64][65];
    __shared__ int   tl[64];

    if (tid < 64) {
        int j = i0 + tid;
        tl[tid] = (j < mb) ? list[b*CT + j] : 0;
    }
    __syncthreads();

    float acc[4][4] = {};
    int tr = tid >> 4, tc = tid & 15;

    for (int k0 = 0; k0 < EMBED; k0 += 64) {
        #pragma unroll
        for (int e = 0; e < 16; ++e) {
            int flat = tid + 256*e;
            int r = flat >> 6, k = flat & 63;
            int j = i0 + r;
            float va = 0.f, vb = 0.f;
            if (k0 + k < EMBED) {
                if (j < mb)
                    va = emb[((size_t)(b*TSTEPS + tl[r]))*EMBED + k0 + k];
                vb = W_ih[(size_t)(n0 + r)*EMBED + k0 + k];
            }
            As[r][k] = va;
            Bs[r][k] = vb;
        }
        __syncthreads();
        #pragma unroll 8
        for (int k = 0; k < 64; ++k) {
            float a0 = As[tr*4+0][k], a1 = As[tr*4+1][k];
            float a2 = As[tr*4+2][k], a3 = As[tr*4+3][k];
            float b0 = Bs[tc*4+0][k], b1 = Bs[tc*4+1][k];
            float b2 = Bs[tc*4+2][k], b3 = Bs[tc*4+3][k];
            acc[0][0] += a0*b0; acc[0][1] += a0*b1; acc[0][2] += a0*b2; acc[0][3] += a0*b3;
            acc[1][0] += a1*b0; acc[1][1] += a1*b1; acc[1][2] += a1*b2; acc[1][3] += a1*b3;
            acc[2][0] += a2*b0; acc[2][1] += a2*b1; acc[2][2] += a2*b2; acc[2][3] += a2*b3;
            acc[3][0] += a3*b0; acc[3][1] += a3*b1; acc[3][2] += a3*b2; acc[3][3] += a3*b3;
        }
        __syncthreads();
    }

    #pragma unroll
    for (int e = 0; e < 4; ++e) {
        int j = i0 + tr*4 + e;
        if (j < mb) {
            size_t zb = ((size_t)b*CT + j)*GATES + n0 + tc*4;
            Z[zb+0] = acc[e][0]; Z[zb+1] = acc[e][1];
            Z[zb+2] = acc[e][2]; Z[zb+3] = acc[e][3];
        }
    }
}

// ---------------- Kernel 3: recurrent LSTM — ONE block per batch ------------
// EXACT round-7 structure (measured 2130us, 0 bank conflicts, no scratch):
// 512 threads; thread i owns gate-rows {i, 512+i}. W_hh f16: k<64 in LDS
// (WSTRIDE 34, uint2 reads), k in [64,256) as 2x96 h2 register/AGPR-resident.
// ONLY change vs r7: libm tanhf/expf -> native v_exp/v_rcp activations
// (r8's restructure spilled W to scratch: +15MB writes, 4.2x regression).
__global__ __launch_bounds__(512, 2) void k_lstm(
    const float* __restrict__ Z, const int* __restrict__ cnt,
    const float* __restrict__ W_hh,
    const float* __restrict__ b_ih, const float* __restrict__ b_hh,
    float* __restrict__ h_state, float* __restrict__ c_state, int CT)
{
    int b = blockIdx.x;
    int tid = threadIdx.x;            // 0..511
    int d   = tid & 255;              // hidden dim this thread's rows act on
    int rowA = tid;                   // gate (tid>>8)      : 0 or 1
    int rowB = tid + 512;             // gate (tid>>8) + 2  : 2 or 3

    __shared__ unsigned wlds[1024 * WSTRIDE];        // 139,264 B
    __shared__ float act13[2][256];                  // forget, out broadcast
    __shared__ __align__(16) _Float16 h_arr[HID];    // current h (f16)

    // ---- stage W[k<64] into LDS as f16 pairs --------------------------------
    for (int idx = tid; idx < 1024*32; idx += 512) {
        int r = idx >> 5, k = idx & 31;              // k = half2 index (f16 2k,2k+1)
        float2 v = ((const float2*)(W_hh + (size_t)r*HID))[k];
        *(h2*)&wlds[r*WSTRIDE + k] = pack_h2(v.x, v.y);
    }

    // ---- W[k in 64..255] into registers: 96 half2 per row -------------------
    h2 wrA[96], wrB[96];
    {
        const float2* pA = (const float2*)(W_hh + (size_t)rowA*HID);
        const float2* pB = (const float2*)(W_hh + (size_t)rowB*HID);
        #pragma unroll
        for (int t = 0; t < 96; ++t) {
            float2 va = pA[32 + t], vb = pB[32 + t];
            wrA[t] = pack_h2(va.x, va.y);
            wrB[t] = pack_h2(vb.x, vb.y);
        }
    }
    float biasA = b_ih[rowA] + b_hh[rowA];
    float biasB = b_ih[rowB] + b_hh[rowB];

    float c_reg = 0.f;
    if (tid < 256) {
        h_arr[d] = (_Float16)h_state[(size_t)b*HID + d];
        c_reg    = c_state[(size_t)b*HID + d];
    }
    __syncthreads();

    int mb = cnt[b];
    float zAcur = 0.f, zBcur = 0.f;
    if (mb > 0) {
        zAcur = Z[((size_t)b*CT)*GATES + rowA];
        zBcur = Z[((size_t)b*CT)*GATES + rowB];
    }

    for (int j = 0; j < mb; ++j) {
        // prefetch next step's z under the dot
        float zAn = 0.f, zBn = 0.f;
        if (j + 1 < mb) {
            zAn = Z[((size_t)b*CT + j + 1)*GATES + rowA];
            zBn = Z[((size_t)b*CT + j + 1)*GATES + rowB];
        }

        float accA0 = 0.f, accA1 = 0.f, accB0 = 0.f, accB1 = 0.f;
        #pragma unroll
        for (int c = 0; c < 32; ++c) {
            uint4 hv = ((const uint4*)h_arr)[c];     // 8 f16 of h (broadcast)
            h2 h0 = bc_h2(hv.x), h1 = bc_h2(hv.y);
            h2 h2_ = bc_h2(hv.z), h3 = bc_h2(hv.w);
            h2 wA0, wA1, wA2, wA3, wB0, wB1, wB2, wB3;
            if (c < 8) {
                uint2 a01 = *(const uint2*)&wlds[rowA*WSTRIDE + 4*c];
                uint2 a23 = *(const uint2*)&wlds[rowA*WSTRIDE + 4*c + 2];
                uint2 b01 = *(const uint2*)&wlds[rowB*WSTRIDE + 4*c];
                uint2 b23 = *(const uint2*)&wlds[rowB*WSTRIDE + 4*c + 2];
                wA0 = bc_h2(a01.x); wA1 = bc_h2(a01.y);
                wA2 = bc_h2(a23.x); wA3 = bc_h2(a23.y);
                wB0 = bc_h2(b01.x); wB1 = bc_h2(b01.y);
                wB2 = bc_h2(b23.x); wB3 = bc_h2(b23.y);
            } else {
                int t = (c - 8) * 4;
                wA0 = wrA[t+0]; wA1 = wrA[t+1]; wA2 = wrA[t+2]; wA3 = wrA[t+3];
                wB0 = wrB[t+0]; wB1 = wrB[t+1]; wB2 = wrB[t+2]; wB3 = wrB[t+3];
            }
            accA0 = dot2f(wA0, h0, accA0);
            accA1 = dot2f(wA1, h1, accA1);
            accA0 = dot2f(wA2, h2_, accA0);
            accA1 = dot2f(wA3, h3, accA1);
            accB0 = dot2f(wB0, h0, accB0);
            accB1 = dot2f(wB1, h1, accB1);
            accB0 = dot2f(wB2, h2_, accB0);
            accB1 = dot2f(wB3, h3, accB1);
        }
        float aF = zAcur + biasA + (accA0 + accA1);   // gate input(i<256)/forget
        float aS = zBcur + biasB + (accB0 + accB1);   // gate cellcand / out

        float iv = 0.f, gv = 0.f;
        if (tid < 256) {
            iv = sigm_(aF);                 // input gate
            gv = tanh_(aS);                 // cell candidate
        } else {
            act13[0][d] = sigm_(aF);        // forget gate
            act13[1][d] = sigm_(aS);        // output gate
        }
        __syncthreads();   // act13 ready; everyone done reading h_arr

        if (tid < 256) {
            float fv = act13[0][d], ov = act13[1][d];
            c_reg = fv * c_reg + iv * gv;
            float hn = ov * tanh_(c_reg);
            h_arr[d] = (_Float16)hn;
        }
        __syncthreads();   // h_arr ready for next step
        zAcur = zAn; zBcur = zBn;
    }

    if (tid < 256) {
        h_state[(size_t)b*HID + d] = (float)h_arr[d];
        c_state[(size_t)b*HID + d] = c_reg;
    }
}

// ---------------- Kernel 4: logits -> softmax -> argmax ---------------------
__global__ __launch_bounds__(64) void k_final(
    const float* __restrict__ h_state, const float* __restrict__ W_out,
    const float* __restrict__ b_out, float* __restrict__ out)
{
    int b = threadIdx.x;   // 64 threads
    float l0 = b_out[0], l1 = b_out[1];
    for (int k = 0; k < HID; ++k) {
        float h = h_state[b*HID + k];
        l0 += h * W_out[k];
        l1 += h * W_out[HID + k];
    }
    float m  = fmaxf(l0, l1);
    float e0 = expf(l0 - m), e1 = expf(l1 - m);
    float s  = e0 + e1;
    float p0 = e0 / s, p1 = e1 / s;
    out[b*2 + 0] = p0;
    out[b*2 + 1] = p1;
    out[BATCH*2 + b] = (p1 > p0) ? 1.0f : 0.0f;  // argmax, first-index tiebreak
}

// ---------------- host ------------------------------------------------------
extern "C" void kernel_launch(void* const* d_in, const int* in_sizes, int n_in,
                              void* d_out, int out_size, void* d_ws, size_t ws_size,
                              hipStream_t stream)
{
    (void)in_sizes; (void)n_in; (void)out_size;
    const float* emb   = (const float*)d_in[0];
    const float* mask  = (const float*)d_in[1];
    const int*   len   = (const int*)  d_in[2];
    const float* W_ih  = (const float*)d_in[3];
    const float* W_hh  = (const float*)d_in[4];
    const float* b_ih  = (const float*)d_in[5];
    const float* b_hh  = (const float*)d_in[6];
    const float* W_out = (const float*)d_in[7];
    const float* b_out = (const float*)d_in[8];
    float* out = (float*)d_out;

    char* p = (char*)d_ws;
    auto carve = [&](size_t bytes) -> char* {
        char* r = p;
        p += (bytes + 255) & ~(size_t)255;
        return r;
    };
    float* h_state = (float*)carve((size_t)BATCH*HID*4);
    float* c_state = (float*)carve((size_t)BATCH*HID*4);
    int*   cntb    = (int*)  carve((size_t)BATCH*4);

    size_t fixed = (size_t)(p - (char*)d_ws);
    int CT = TSTEPS;  // shrink to fit workspace
    while (CT > 64) {
        size_t lb = (((size_t)BATCH*CT*4) + 255) & ~(size_t)255;
        size_t zb = (size_t)BATCH*CT*GATES*4;
        if (fixed + lb + zb + 1024 <= ws_size) break;
        CT >>= 1;
    }
    int*   list = (int*)  carve((size_t)BATCH*CT*4);
    float* Z    = (float*)carve((size_t)BATCH*CT*GATES*4);

    int nchunks = TSTEPS / CT;
    for (int c = 0; c < nchunks; ++c) {
        int t0 = c * CT;
        int first = (c == 0) ? 1 : 0;
        hipLaunchKernelGGL(k_compact, dim3(BATCH), dim3(256), 0, stream,
                           mask, len, list, cntb, h_state, c_state,
                           t0, CT, first);
        hipLaunchKernelGGL(k_gemm, dim3(16, CT/64, BATCH), dim3(256), 0, stream,
                           emb, W_ih, list, cntb, Z, CT);
        hipLaunchKernelGGL(k_lstm, dim3(BATCH), dim3(512), 0, stream,
                           Z, cntb, W_hh, b_ih, b_hh,
                           h_state, c_state, CT);
    }
    hipLaunchKernelGGL(k_final, dim3(1), dim3(64), 0, stream,
                       h_state, W_out, b_out, out);
}